// Round 2
// baseline (1602.215 us; speedup 1.0000x reference)
//
#include <hip/hip_runtime.h>
#include <math.h>

using bf16x8 = __attribute__((ext_vector_type(8))) short;
using f32x4  = __attribute__((ext_vector_type(4))) float;
typedef unsigned short u16;

#define DI __device__ __forceinline__

DI u16 f2bf(float f){
  union { float f; unsigned u; } v; v.f = f;
  return (u16)((v.u + 0x7fffu + ((v.u >> 16) & 1u)) >> 16);
}

// ---------------- fp32 -> bf16 convert ----------------
__global__ void k_cvt(const float* __restrict__ in, u16* __restrict__ out, int n4){
  int i = blockIdx.x * 256 + threadIdx.x;
  if (i >= n4) return;
  float4 v = ((const float4*)in)[i];
  short4 o;
  o.x = (short)f2bf(v.x); o.y = (short)f2bf(v.y);
  o.z = (short)f2bf(v.z); o.w = (short)f2bf(v.w);
  ((short4*)out)[i] = o;
}

// ---------------- NCHW fp32 -> [token][C] bf16 transpose ----------------
__global__ void k_xpose(const float* __restrict__ x, u16* __restrict__ xT){
  __shared__ float tile[64][65];
  int hw0 = blockIdx.x * 64, c0 = blockIdx.y * 64, b = blockIdx.z;
  int tid = threadIdx.x;
  const float* src = x + ((size_t)(b * 512 + c0)) * 4096 + hw0;
  for (int rep = 0; rep < 16; rep++){
    int idx = rep * 256 + tid;
    int cc = idx >> 6, th = idx & 63;
    tile[cc][th] = src[(size_t)cc * 4096 + th];
  }
  __syncthreads();
  u16* dst = xT + ((size_t)(b * 4096 + hw0)) * 512 + c0;
  for (int rep = 0; rep < 16; rep++){
    int idx = rep * 256 + tid;
    int tt = idx >> 6, cc = idx & 63;
    dst[(size_t)tt * 512 + cc] = f2bf(tile[cc][tt]);
  }
}

// ---------------- LayerNorm (C=256), one wave per token ----------------
__global__ void k_ln(const float* __restrict__ xin, const float* __restrict__ g,
                     const float* __restrict__ bta, u16* __restrict__ out){
  int t = blockIdx.x * 4 + (threadIdx.x >> 6);
  int lane = threadIdx.x & 63;
  float4 v = ((const float4*)(xin + (size_t)t * 256))[lane];
  float s  = v.x + v.y + v.z + v.w;
  float s2 = v.x*v.x + v.y*v.y + v.z*v.z + v.w*v.w;
  for (int m = 1; m < 64; m <<= 1){ s += __shfl_xor(s, m, 64); s2 += __shfl_xor(s2, m, 64); }
  float mu  = s * (1.0f/256.0f);
  float var = s2 * (1.0f/256.0f) - mu*mu;
  float inv = rsqrtf(var + 1e-5f);
  float4 gg = ((const float4*)g)[lane];
  float4 bb = ((const float4*)bta)[lane];
  short4 o;
  o.x = (short)f2bf((v.x - mu) * inv * gg.x + bb.x);
  o.y = (short)f2bf((v.y - mu) * inv * gg.y + bb.y);
  o.z = (short)f2bf((v.z - mu) * inv * gg.z + bb.z);
  o.w = (short)f2bf((v.w - mu) * inv * gg.w + bb.w);
  ((short4*)(out + (size_t)t * 256))[lane] = o;
}

// ---------------- generic bf16 MFMA GEMM: C[M][N] = A[M][K] * W[N][K]^T ----------------
// MODE 0: BN+SiLU -> fp32 out             (cv1)
// MODE 1: BN+SiLU -> bf16 out             (cv2)
// MODE 2: +bias   -> bf16 out             (qkv)
// MODE 3: +bias +resid -> fp32 out        (proj, fc2 l0)
// MODE 4: +bias GELU -> bf16 out          (fc1)
// MODE 5: +bias +resid -> fp32 + bf16 dual(fc2 l1)
// MODE 6: split-A (A:k<256, A2:k>=256, ld 256 each); BN+SiLU -> fp32 NCHW d_out
struct GemmP {
  const u16* A; const u16* A2; const u16* W;
  int K; int N;
  const float* bias;     // bias, or BN params (4 rows of bnN)
  int bnN;
  const float* resid; int ldR;
  float* outF; int ldF;
  u16* outB; int ldB; int colB;
};

template<int MODE>
__launch_bounds__(256)
__global__ void k_gemm(GemmP p){
  __shared__ __align__(16) u16 sA[128 * 32];
  __shared__ __align__(16) u16 sB[128 * 32];
  __shared__ float sT[(MODE == 6) ? 32 * 136 : 1];
  int tid = threadIdx.x;
  int wave = tid >> 6, lane = tid & 63;
  int fq = lane >> 4, fr = lane & 15;
  int m0 = blockIdx.x * 128, n0 = blockIdx.y * 128;
  int wm = (wave >> 1) * 64, wn = (wave & 1) * 64;

  f32x4 acc[4][4];
  f32x4 z4 = {0.f, 0.f, 0.f, 0.f};
  #pragma unroll
  for (int i = 0; i < 4; i++)
    #pragma unroll
    for (int j = 0; j < 4; j++) acc[i][j] = z4;

  for (int k0 = 0; k0 < p.K; k0 += 32){
    #pragma unroll
    for (int i = 0; i < 2; i++){
      int chunk = i * 256 + tid;           // 512 chunks of 8 bf16
      int row = chunk >> 2, ko = (chunk & 3) << 3;
      if constexpr (MODE == 6){
        const u16* base = (k0 < 256) ? p.A : p.A2;
        *(bf16x8*)(sA + row * 32 + ko) =
            *(const bf16x8*)(base + (size_t)(m0 + row) * 256 + (k0 & 255) + ko);
      } else {
        *(bf16x8*)(sA + row * 32 + ko) =
            *(const bf16x8*)(p.A + (size_t)(m0 + row) * p.K + k0 + ko);
      }
      *(bf16x8*)(sB + row * 32 + ko) = *(const bf16x8*)(p.W + (size_t)(n0 + row) * p.K + k0 + ko);
    }
    __syncthreads();
    bf16x8 af[4], bfr[4];
    #pragma unroll
    for (int i = 0; i < 4; i++) af[i]  = *(const bf16x8*)(sA + (wm + i * 16 + fr) * 32 + fq * 8);
    #pragma unroll
    for (int j = 0; j < 4; j++) bfr[j] = *(const bf16x8*)(sB + (wn + j * 16 + fr) * 32 + fq * 8);
    #pragma unroll
    for (int i = 0; i < 4; i++)
      #pragma unroll
      for (int j = 0; j < 4; j++)
        acc[i][j] = __builtin_amdgcn_mfma_f32_16x16x32_bf16(af[i], bfr[j], acc[i][j], 0, 0, 0);
    __syncthreads();
  }

  if constexpr (MODE != 6){
    #pragma unroll
    for (int j = 0; j < 4; j++){
      int col = n0 + wn + j * 16 + fr;
      float sc = 0.f, sh = 0.f;
      if constexpr (MODE == 0 || MODE == 1){
        float gg = p.bias[col];
        float bb = p.bias[p.bnN + col];
        float mv = p.bias[2 * p.bnN + col];
        float vv = p.bias[3 * p.bnN + col];
        sc = gg * rsqrtf(vv + 1e-5f);
        sh = bb - mv * sc;
      } else {
        sh = p.bias[col];
      }
      #pragma unroll
      for (int i = 0; i < 4; i++){
        #pragma unroll
        for (int rr = 0; rr < 4; rr++){
          int row = m0 + wm + i * 16 + fq * 4 + rr;
          float v = acc[i][j][rr];
          if constexpr (MODE == 0 || MODE == 1){ v = v * sc + sh; v = v / (1.f + __expf(-v)); }
          else v += sh;
          if constexpr (MODE == 3 || MODE == 5) v += p.resid[(size_t)row * p.ldR + col];
          if constexpr (MODE == 4) v = 0.5f * v * (1.f + erff(v * 0.70710678118f));
          if constexpr (MODE == 0 || MODE == 3 || MODE == 5) p.outF[(size_t)row * p.ldF + col] = v;
          if constexpr (MODE == 1 || MODE == 2 || MODE == 4 || MODE == 5)
            p.outB[(size_t)row * p.ldB + p.colB + col] = f2bf(v);
        }
      }
    }
  } else {
    // BN+SiLU then fp32 NCHW store via LDS transpose (4 passes of 32 channels)
    int b = m0 >> 12;
    int hw0 = m0 & 4095;
    #pragma unroll
    for (int ps = 0; ps < 4; ps++){
      if (wn == (ps >> 1) * 64){
        #pragma unroll
        for (int jj = 0; jj < 2; jj++){
          int j = (ps & 1) * 2 + jj;
          int col = n0 + wn + j * 16 + fr;
          float gg = p.bias[col];
          float bb = p.bias[p.bnN + col];
          float mv = p.bias[2 * p.bnN + col];
          float vv = p.bias[3 * p.bnN + col];
          float sc = gg * rsqrtf(vv + 1e-5f);
          float sh = bb - mv * sc;
          int nl = wn + j * 16 + fr - ps * 32;
          #pragma unroll
          for (int i = 0; i < 4; i++)
            #pragma unroll
            for (int rr = 0; rr < 4; rr++){
              float v = acc[i][j][rr];
              v = v * sc + sh; v = v / (1.f + __expf(-v));
              sT[nl * 136 + wm + i * 16 + fq * 4 + rr] = v;
            }
        }
      }
      __syncthreads();
      for (int rep = 0; rep < 16; rep++){
        int flat = rep * 256 + tid;
        int nl = flat >> 7, ml = flat & 127;
        int c = n0 + ps * 32 + nl;
        p.outF[((size_t)(b * 512 + c)) * 4096 + hw0 + ml] = sT[nl * 136 + ml];
      }
      __syncthreads();
    }
  }
}

// ---------------- windowed attention: one block per window, 4 waves x 2 heads ----------------
template<int SHIFT>
__launch_bounds__(256)
__global__ void k_attn(const u16* __restrict__ qkv, const float* __restrict__ rpb,
                       u16* __restrict__ out){
  __shared__ int tmap[64];
  __shared__ float bias_s[1800];
  __shared__ __align__(16) u16 p_s[4][64][72];
  __shared__ __align__(16) u16 vT_s[4][32][72];
  int tid = threadIdx.x, wave = tid >> 6, lane = tid & 63;
  int fq = lane >> 4, fr = lane & 15;
  int wi = blockIdx.x;
  int b = wi >> 6, wh = (wi >> 3) & 7, ww = wi & 7;

  for (int i = tid; i < 1800; i += 256) bias_s[i] = rpb[i];
  if (tid < 64){
    int r = tid >> 3, c = tid & 7;
    int h = (wh * 8 + r + SHIFT) & 63;
    int w = (ww * 8 + c + SHIFT) & 63;
    tmap[tid] = (b << 12) | (h << 6) | w;
  }
  __syncthreads();

  const float scl = 0.17677669529663687f;  // 1/sqrt(32)
  for (int hh = 0; hh < 2; hh++){
    int head = wave * 2 + hh;

    // stage V^T for this head (rows=dim, cols=token)
    {
      const u16* vrow = qkv + (size_t)tmap[lane] * 768 + 512 + head * 32;
      #pragma unroll
      for (int cg = 0; cg < 4; cg++){
        bf16x8 vv = *(const bf16x8*)(vrow + cg * 8);
        #pragma unroll
        for (int e = 0; e < 8; e++) vT_s[wave][cg * 8 + e][lane] = (u16)vv[e];
      }
    }

    // QK^T (K-dim = 32 -> one mfma step per 16x16 fragment)
    bf16x8 qf[4], kf[4];
    #pragma unroll
    for (int i = 0; i < 4; i++){
      int n = i * 16 + fr;
      size_t base = (size_t)tmap[n] * 768 + head * 32 + fq * 8;
      qf[i] = *(const bf16x8*)(qkv + base);
      kf[i] = *(const bf16x8*)(qkv + base + 256);
    }
    f32x4 z4 = {0.f, 0.f, 0.f, 0.f};
    f32x4 sfr[4][4];
    #pragma unroll
    for (int i = 0; i < 4; i++)
      #pragma unroll
      for (int j = 0; j < 4; j++) sfr[i][j] = z4;
    #pragma unroll
    for (int i = 0; i < 4; i++)
      #pragma unroll
      for (int j = 0; j < 4; j++)
        sfr[i][j] = __builtin_amdgcn_mfma_f32_16x16x32_bf16(qf[i], kf[j], sfr[i][j], 0, 0, 0);

    // softmax rows: row rq = i*16 + fq*4 + rr ; cols j*16 + fr ; reduce over 16 lanes (fr)
    #pragma unroll
    for (int i = 0; i < 4; i++){
      #pragma unroll
      for (int rr = 0; rr < 4; rr++){
        int rq = i * 16 + fq * 4 + rr;
        int prq = rq >> 3, pcq = rq & 7;
        int idq = 0;
        if (SHIFT > 0){
          int rh = (wh == 7) ? ((prq >= 4) ? 2 : 1) : 0;
          int rw = (ww == 7) ? ((pcq >= 4) ? 2 : 1) : 0;
          idq = rh * 3 + rw;
        }
        float vv[4];
        float mx = -1e30f;
        #pragma unroll
        for (int j = 0; j < 4; j++){
          int m = j * 16 + fr;
          int prk = m >> 3, pck = m & 7;
          float bi = bias_s[((prq - prk + 7) * 15 + (pcq - pck + 7)) * 8 + head];
          float v = sfr[i][j][rr] * scl + bi;
          if (SHIFT > 0){
            int rhk = (wh == 7) ? ((prk >= 4) ? 2 : 1) : 0;
            int rwk = (ww == 7) ? ((pck >= 4) ? 2 : 1) : 0;
            if (idq != rhk * 3 + rwk) v -= 100.f;
          }
          vv[j] = v;
          mx = fmaxf(mx, v);
        }
        for (int mm = 1; mm < 16; mm <<= 1) mx = fmaxf(mx, __shfl_xor(mx, mm, 64));
        float sum = 0.f;
        #pragma unroll
        for (int j = 0; j < 4; j++){ vv[j] = __expf(vv[j] - mx); sum += vv[j]; }
        for (int mm = 1; mm < 16; mm <<= 1) sum += __shfl_xor(sum, mm, 64);
        float inv = 1.0f / sum;
        #pragma unroll
        for (int j = 0; j < 4; j++) p_s[wave][rq][j * 16 + fr] = f2bf(vv[j] * inv);
      }
    }
    __syncthreads();   // p_s + vT_s visible

    // O = P(64x64) * V(64x32)
    f32x4 o[4][2];
    #pragma unroll
    for (int i = 0; i < 4; i++){ o[i][0] = z4; o[i][1] = z4; }
    #pragma unroll
    for (int ks = 0; ks < 2; ks++){
      bf16x8 pa[4], vb[2];
      #pragma unroll
      for (int i = 0; i < 4; i++) pa[i] = *(const bf16x8*)&p_s[wave][i * 16 + fr][ks * 32 + fq * 8];
      #pragma unroll
      for (int j = 0; j < 2; j++) vb[j] = *(const bf16x8*)&vT_s[wave][j * 16 + fr][ks * 32 + fq * 8];
      #pragma unroll
      for (int i = 0; i < 4; i++)
        #pragma unroll
        for (int j = 0; j < 2; j++)
          o[i][j] = __builtin_amdgcn_mfma_f32_16x16x32_bf16(pa[i], vb[j], o[i][j], 0, 0, 0);
    }
    // store: row rq -> token tmap[rq], channel = head*32 + j*16 + fr
    #pragma unroll
    for (int i = 0; i < 4; i++)
      #pragma unroll
      for (int j = 0; j < 2; j++)
        #pragma unroll
        for (int rr = 0; rr < 4; rr++){
          int rq = i * 16 + fq * 4 + rr;
          int t = tmap[rq];
          out[(size_t)t * 256 + head * 32 + j * 16 + fr] = f2bf(o[i][j][rr]);
        }
    __syncthreads();   // before next head overwrites LDS
  }
}

// ---------------- host ----------------
extern "C" void kernel_launch(void* const* d_in, const int* in_sizes, int n_in,
                              void* d_out, int out_size, void* d_ws, size_t ws_size,
                              hipStream_t stream){
  (void)in_sizes; (void)n_in; (void)out_size; (void)ws_size;
  const float* x      = (const float*)d_in[0];
  const float* cv1_w  = (const float*)d_in[1];
  const float* cv1_bn = (const float*)d_in[2];
  const float* cv2_w  = (const float*)d_in[3];
  const float* cv2_bn = (const float*)d_in[4];
  const float* cv3_w  = (const float*)d_in[5];
  const float* cv3_bn = (const float*)d_in[6];
  const float* n1g = (const float*)d_in[7];
  const float* n1b = (const float*)d_in[8];
  const float* qkvw = (const float*)d_in[9];
  const float* qkvb = (const float*)d_in[10];
  const float* pw  = (const float*)d_in[11];
  const float* pb  = (const float*)d_in[12];
  const float* rpb = (const float*)d_in[13];
  const float* n2g = (const float*)d_in[14];
  const float* n2b = (const float*)d_in[15];
  const float* f1w = (const float*)d_in[16];
  const float* f1b = (const float*)d_in[17];
  const float* f2w = (const float*)d_in[18];
  const float* f2b = (const float*)d_in[19];

  char* ws = (char*)d_ws;
  const size_t MB = 1024 * 1024;
  // layout (peak 360 MB):
  // [0,32)   ln_o  (also xT low half; also yF = final-y bf16 during fc2-l1/cv3)
  // [32,64)  at_o  (also xT high half)
  // [64,192) qkvB / hB
  // [192,256) yS fp32 residual stream
  // [256,320) x1 fp32
  // [320,328) wp bf16 weights
  // [328,360) y2 (cv2 out bf16)
  u16*   xT   = (u16*)(ws);
  u16*   ln_o = (u16*)(ws);
  u16*   yF   = (u16*)(ws);
  u16*   at_o = (u16*)(ws + 32 * MB);
  u16*   qkvB = (u16*)(ws + 64 * MB);
  u16*   hB   = qkvB;
  float* yS   = (float*)(ws + 192 * MB);
  float* x1   = (float*)(ws + 256 * MB);
  u16*   wp   = (u16*)(ws + 320 * MB);
  u16*   y2   = (u16*)(ws + 328 * MB);

  u16* wCv1 = wp;
  u16* wCv2 = wp + 131072;
  u16* wCv3 = wp + 262144;
  u16* wQkv = wp + 524288;
  u16* wPrj = wp + 917504;
  u16* wF1  = wp + 1048576;
  u16* wF2  = wp + 1572864;

  auto cvt = [&](const float* src, u16* dst, int n){
    int n4 = n >> 2;
    k_cvt<<<(n4 + 255) / 256, 256, 0, stream>>>(src, dst, n4);
  };
  cvt(cv1_w, wCv1, 131072);
  cvt(cv2_w, wCv2, 131072);
  cvt(cv3_w, wCv3, 262144);
  cvt(qkvw,  wQkv, 393216);
  cvt(pw,    wPrj, 131072);
  cvt(f1w,   wF1,  524288);
  cvt(f2w,   wF2,  524288);

  k_xpose<<<dim3(64, 8, 16), 256, 0, stream>>>(x, xT);

  const int M = 65536;
  auto gemm = [&](int mode, const u16* A, const u16* A2, const u16* W, int K, int N,
                  const float* bias, int bnN, const float* resid, int ldR,
                  float* outF, int ldF, u16* outB, int ldB, int colB){
    GemmP p{A, A2, W, K, N, bias, bnN, resid, ldR, outF, ldF, outB, ldB, colB};
    dim3 g(M / 128, N / 128);
    switch (mode){
      case 0: k_gemm<0><<<g, 256, 0, stream>>>(p); break;
      case 1: k_gemm<1><<<g, 256, 0, stream>>>(p); break;
      case 2: k_gemm<2><<<g, 256, 0, stream>>>(p); break;
      case 3: k_gemm<3><<<g, 256, 0, stream>>>(p); break;
      case 4: k_gemm<4><<<g, 256, 0, stream>>>(p); break;
      case 5: k_gemm<5><<<g, 256, 0, stream>>>(p); break;
      case 6: k_gemm<6><<<g, 256, 0, stream>>>(p); break;
    }
  };

  // cv1 -> yS (fp32 residual stream) ; cv2 -> y2 bf16
  gemm(0, xT, nullptr, wCv1, 512, 256, cv1_bn, 256, nullptr, 0, yS, 256, nullptr, 0, 0);
  gemm(1, xT, nullptr, wCv2, 512, 256, cv2_bn, 256, nullptr, 0, nullptr, 0, y2, 256, 0);

  for (int l = 0; l < 2; l++){
    k_ln<<<16384, 256, 0, stream>>>(yS, n1g + l * 256, n1b + l * 256, ln_o);
    gemm(2, ln_o, nullptr, wQkv + l * 196608, 256, 768, qkvb + l * 768, 0, nullptr, 0,
         nullptr, 0, qkvB, 768, 0);
    if (l == 0) k_attn<0><<<1024, 256, 0, stream>>>(qkvB, rpb, at_o);
    else        k_attn<4><<<1024, 256, 0, stream>>>(qkvB, rpb + 1800, at_o);
    gemm(3, at_o, nullptr, wPrj + l * 65536, 256, 256, pb + l * 256, 0, yS, 256,
         x1, 256, nullptr, 0, 0);
    k_ln<<<16384, 256, 0, stream>>>(x1, n2g + l * 256, n2b + l * 256, ln_o);
    gemm(4, ln_o, nullptr, wF1 + l * 262144, 256, 1024, f1b + l * 1024, 0, nullptr, 0,
         nullptr, 0, hB, 1024, 0);
    if (l == 0)
      gemm(3, hB, nullptr, wF2 + l * 262144, 1024, 256, f2b + l * 256, 0, x1, 256,
           yS, 256, nullptr, 0, 0);
    else
      gemm(5, hB, nullptr, wF2 + l * 262144, 1024, 256, f2b + l * 256, 0, x1, 256,
           yS, 256, yF, 256, 0);
  }

  // cv3: A = [yF | y2] (split at k=256) -> BN+SiLU -> d_out fp32 NCHW
  gemm(6, yF, y2, wCv3, 512, 512, cv3_bn, 512, nullptr, 0,
       (float*)d_out, 0, nullptr, 0, 0);
}

// Round 3
// 1409.260 us; speedup vs baseline: 1.1369x; 1.1369x over previous
//
#include <hip/hip_runtime.h>
#include <math.h>

using bf16x8 = __attribute__((ext_vector_type(8))) short;
using f32x4  = __attribute__((ext_vector_type(4))) float;
typedef unsigned short u16;

#define DI __device__ __forceinline__

DI u16 f2bf(float f){
  union { float f; unsigned u; } v; v.f = f;
  return (u16)((v.u + 0x7fffu + ((v.u >> 16) & 1u)) >> 16);
}

// async global->LDS, 16B per lane; LDS dest = wave-uniform base + lane*16
DI void gll16(const void* g, void* l){
  __builtin_amdgcn_global_load_lds((const __attribute__((address_space(1))) void*)g,
                                   (__attribute__((address_space(3))) void*)l, 16, 0, 0);
}

// ---------------- fp32 -> bf16 convert ----------------
__global__ void k_cvt(const float* __restrict__ in, u16* __restrict__ out, int n4){
  int i = blockIdx.x * 256 + threadIdx.x;
  if (i >= n4) return;
  float4 v = ((const float4*)in)[i];
  short4 o;
  o.x = (short)f2bf(v.x); o.y = (short)f2bf(v.y);
  o.z = (short)f2bf(v.z); o.w = (short)f2bf(v.w);
  ((short4*)out)[i] = o;
}

// ---------------- NCHW fp32 -> [token][C] bf16 transpose ----------------
__global__ void k_xpose(const float* __restrict__ x, u16* __restrict__ xT){
  __shared__ float tile[64][65];
  int hw0 = blockIdx.x * 64, c0 = blockIdx.y * 64, b = blockIdx.z;
  int tid = threadIdx.x;
  const float* src = x + ((size_t)(b * 512 + c0)) * 4096 + hw0;
  for (int rep = 0; rep < 16; rep++){
    int idx = rep * 256 + tid;
    int cc = idx >> 6, th = idx & 63;
    tile[cc][th] = src[(size_t)cc * 4096 + th];
  }
  __syncthreads();
  u16* dst = xT + ((size_t)(b * 4096 + hw0)) * 512 + c0;
  for (int rep = 0; rep < 16; rep++){
    int idx = rep * 256 + tid;
    int tt = idx >> 6, cc = idx & 63;
    dst[(size_t)tt * 512 + cc] = f2bf(tile[cc][tt]);
  }
}

// ---------------- LayerNorm (C=256), one wave per token ----------------
__global__ void k_ln(const float* __restrict__ xin, const float* __restrict__ g,
                     const float* __restrict__ bta, u16* __restrict__ out){
  int t = blockIdx.x * 4 + (threadIdx.x >> 6);
  int lane = threadIdx.x & 63;
  float4 v = ((const float4*)(xin + (size_t)t * 256))[lane];
  float s  = v.x + v.y + v.z + v.w;
  float s2 = v.x*v.x + v.y*v.y + v.z*v.z + v.w*v.w;
  for (int m = 1; m < 64; m <<= 1){ s += __shfl_xor(s, m, 64); s2 += __shfl_xor(s2, m, 64); }
  float mu  = s * (1.0f/256.0f);
  float var = s2 * (1.0f/256.0f) - mu*mu;
  float inv = rsqrtf(var + 1e-5f);
  float4 gg = ((const float4*)g)[lane];
  float4 bb = ((const float4*)bta)[lane];
  short4 o;
  o.x = (short)f2bf((v.x - mu) * inv * gg.x + bb.x);
  o.y = (short)f2bf((v.y - mu) * inv * gg.y + bb.y);
  o.z = (short)f2bf((v.z - mu) * inv * gg.z + bb.z);
  o.w = (short)f2bf((v.w - mu) * inv * gg.w + bb.w);
  ((short4*)(out + (size_t)t * 256))[lane] = o;
}

// ---------------- generic bf16 MFMA GEMM: C[M][N] = A[M][K] * W[N][K]^T ----------------
// BK=64, global_load_lds staging, XOR chunk-swizzle (source+read, linear LDS dest).
// MODE 0: BN+SiLU -> fp32 out             (cv1)
// MODE 1: BN+SiLU -> bf16 out             (cv2)
// MODE 2: +bias   -> bf16 out             (qkv)
// MODE 3: +bias +resid -> fp32 out        (proj, fc2 l0)
// MODE 4: +bias GELU -> bf16 out          (fc1)
// MODE 5: +bias +resid -> fp32 + bf16 dual(fc2 l1)
// MODE 6: split-A (A:k<256, A2:k>=256, ld 256 each); BN+SiLU -> fp32 NCHW d_out
struct GemmP {
  const u16* A; const u16* A2; const u16* W;
  int K; int N;
  const float* bias;     // bias, or BN params (4 rows of bnN)
  int bnN;
  const float* resid; int ldR;
  float* outF; int ldF;
  u16* outB; int ldB; int colB;
};

template<int MODE>
__launch_bounds__(256)
__global__ void k_gemm(GemmP p){
  __shared__ __align__(16) u16 sA[128 * 64];   // 16 KB, row stride 64 elems
  __shared__ __align__(16) u16 sB[128 * 64];   // 16 KB
  __shared__ float sT[(MODE == 6) ? 32 * 136 : 1];
  int tid = threadIdx.x;
  int wave = tid >> 6, lane = tid & 63;
  int fq = lane >> 4, fr = lane & 15;
  int m0 = blockIdx.x * 128, n0 = blockIdx.y * 128;
  int wm = (wave >> 1) * 64, wn = (wave & 1) * 64;
  const int K = p.K;

  // staging geometry: 1024 chunks of 16B per tile; lane covers (row = l>>3, chunk = l&7)
  int rsub = lane >> 3;                  // 0..7 row within wave's 8-row stripe
  int gk   = ((lane & 7) ^ rsub) << 3;   // swizzled k-offset (elems) within 64-elem window

  f32x4 acc[4][4];
  f32x4 z4 = {0.f, 0.f, 0.f, 0.f};
  #pragma unroll
  for (int i = 0; i < 4; i++)
    #pragma unroll
    for (int j = 0; j < 4; j++) acc[i][j] = z4;

  for (int k0 = 0; k0 < K; k0 += 64){
    #pragma unroll
    for (int it = 0; it < 4; it++){
      int row = (it * 4 + wave) * 8 + rsub;
      const u16* ga;
      if constexpr (MODE == 6){
        const u16* base = (k0 < 256) ? p.A : p.A2;
        ga = base + (size_t)(m0 + row) * 256 + (k0 & 255) + gk;
      } else {
        ga = p.A + (size_t)(m0 + row) * K + k0 + gk;
      }
      gll16(ga, sA + (it * 4 + wave) * 512);
      const u16* gb = p.W + (size_t)(n0 + row) * K + k0 + gk;
      gll16(gb, sB + (it * 4 + wave) * 512);
    }
    __syncthreads();
    #pragma unroll
    for (int kk = 0; kk < 2; kk++){
      bf16x8 af[4], bfr[4];
      #pragma unroll
      for (int i = 0; i < 4; i++){
        int r = wm + i * 16 + fr;
        af[i] = *(const bf16x8*)(sA + r * 64 + ((((kk << 2) + fq) ^ (fr & 7)) << 3));
      }
      #pragma unroll
      for (int j = 0; j < 4; j++){
        int r = wn + j * 16 + fr;
        bfr[j] = *(const bf16x8*)(sB + r * 64 + ((((kk << 2) + fq) ^ (fr & 7)) << 3));
      }
      #pragma unroll
      for (int i = 0; i < 4; i++)
        #pragma unroll
        for (int j = 0; j < 4; j++)
          acc[i][j] = __builtin_amdgcn_mfma_f32_16x16x32_bf16(af[i], bfr[j], acc[i][j], 0, 0, 0);
    }
    __syncthreads();
  }

  if constexpr (MODE != 6){
    #pragma unroll
    for (int j = 0; j < 4; j++){
      int col = n0 + wn + j * 16 + fr;
      float sc = 0.f, sh = 0.f;
      if constexpr (MODE == 0 || MODE == 1){
        float gg = p.bias[col];
        float bb = p.bias[p.bnN + col];
        float mv = p.bias[2 * p.bnN + col];
        float vv = p.bias[3 * p.bnN + col];
        sc = gg * rsqrtf(vv + 1e-5f);
        sh = bb - mv * sc;
      } else {
        sh = p.bias[col];
      }
      #pragma unroll
      for (int i = 0; i < 4; i++){
        #pragma unroll
        for (int rr = 0; rr < 4; rr++){
          int row = m0 + wm + i * 16 + fq * 4 + rr;
          float v = acc[i][j][rr];
          if constexpr (MODE == 0 || MODE == 1){ v = v * sc + sh; v = v / (1.f + __expf(-v)); }
          else v += sh;
          if constexpr (MODE == 3 || MODE == 5) v += p.resid[(size_t)row * p.ldR + col];
          if constexpr (MODE == 4) v = 0.5f * v * (1.f + erff(v * 0.70710678118f));
          if constexpr (MODE == 0 || MODE == 3 || MODE == 5) p.outF[(size_t)row * p.ldF + col] = v;
          if constexpr (MODE == 1 || MODE == 2 || MODE == 4 || MODE == 5)
            p.outB[(size_t)row * p.ldB + p.colB + col] = f2bf(v);
        }
      }
    }
  } else {
    // BN+SiLU then fp32 NCHW store via LDS transpose (4 passes of 32 channels)
    int b = m0 >> 12;
    int hw0 = m0 & 4095;
    #pragma unroll
    for (int ps = 0; ps < 4; ps++){
      if (wn == (ps >> 1) * 64){
        #pragma unroll
        for (int jj = 0; jj < 2; jj++){
          int j = (ps & 1) * 2 + jj;
          int col = n0 + wn + j * 16 + fr;
          float gg = p.bias[col];
          float bb = p.bias[p.bnN + col];
          float mv = p.bias[2 * p.bnN + col];
          float vv = p.bias[3 * p.bnN + col];
          float sc = gg * rsqrtf(vv + 1e-5f);
          float sh = bb - mv * sc;
          int nl = wn + j * 16 + fr - ps * 32;
          #pragma unroll
          for (int i = 0; i < 4; i++)
            #pragma unroll
            for (int rr = 0; rr < 4; rr++){
              float v = acc[i][j][rr];
              v = v * sc + sh; v = v / (1.f + __expf(-v));
              sT[nl * 136 + wm + i * 16 + fq * 4 + rr] = v;
            }
        }
      }
      __syncthreads();
      for (int rep = 0; rep < 16; rep++){
        int flat = rep * 256 + tid;
        int nl = flat >> 7, ml = flat & 127;
        int c = n0 + ps * 32 + nl;
        p.outF[((size_t)(b * 512 + c)) * 4096 + hw0 + ml] = sT[nl * 136 + ml];
      }
      __syncthreads();
    }
  }
}

// ---------------- windowed attention: one block per window, 4 waves x 2 heads ----------------
template<int SHIFT>
__launch_bounds__(256)
__global__ void k_attn(const u16* __restrict__ qkv, const float* __restrict__ rpb,
                       u16* __restrict__ out){
  __shared__ int tmap[64];
  __shared__ float bias_s[1800];
  __shared__ __align__(16) u16 p_s[4][64][72];
  __shared__ __align__(16) u16 vT_s[4][32][72];
  int tid = threadIdx.x, wave = tid >> 6, lane = tid & 63;
  int fq = lane >> 4, fr = lane & 15;
  int wi = blockIdx.x;
  int b = wi >> 6, wh = (wi >> 3) & 7, ww = wi & 7;

  for (int i = tid; i < 1800; i += 256) bias_s[i] = rpb[i];
  if (tid < 64){
    int r = tid >> 3, c = tid & 7;
    int h = (wh * 8 + r + SHIFT) & 63;
    int w = (ww * 8 + c + SHIFT) & 63;
    tmap[tid] = (b << 12) | (h << 6) | w;
  }
  __syncthreads();

  const float scl = 0.17677669529663687f;  // 1/sqrt(32)
  for (int hh = 0; hh < 2; hh++){
    int head = wave * 2 + hh;

    // stage V^T for this head (rows=dim, cols=token)
    {
      const u16* vrow = qkv + (size_t)tmap[lane] * 768 + 512 + head * 32;
      #pragma unroll
      for (int cg = 0; cg < 4; cg++){
        bf16x8 vv = *(const bf16x8*)(vrow + cg * 8);
        #pragma unroll
        for (int e = 0; e < 8; e++) vT_s[wave][cg * 8 + e][lane] = (u16)vv[e];
      }
    }

    // QK^T (K-dim = 32 -> one mfma step per 16x16 fragment)
    bf16x8 qf[4], kf[4];
    #pragma unroll
    for (int i = 0; i < 4; i++){
      int n = i * 16 + fr;
      size_t base = (size_t)tmap[n] * 768 + head * 32 + fq * 8;
      qf[i] = *(const bf16x8*)(qkv + base);
      kf[i] = *(const bf16x8*)(qkv + base + 256);
    }
    f32x4 z4 = {0.f, 0.f, 0.f, 0.f};
    f32x4 sfr[4][4];
    #pragma unroll
    for (int i = 0; i < 4; i++)
      #pragma unroll
      for (int j = 0; j < 4; j++) sfr[i][j] = z4;
    #pragma unroll
    for (int i = 0; i < 4; i++)
      #pragma unroll
      for (int j = 0; j < 4; j++)
        sfr[i][j] = __builtin_amdgcn_mfma_f32_16x16x32_bf16(qf[i], kf[j], sfr[i][j], 0, 0, 0);

    // softmax rows: row rq = i*16 + fq*4 + rr ; cols j*16 + fr ; reduce over 16 lanes (fr)
    #pragma unroll
    for (int i = 0; i < 4; i++){
      #pragma unroll
      for (int rr = 0; rr < 4; rr++){
        int rq = i * 16 + fq * 4 + rr;
        int prq = rq >> 3, pcq = rq & 7;
        int idq = 0;
        if (SHIFT > 0){
          int rh = (wh == 7) ? ((prq >= 4) ? 2 : 1) : 0;
          int rw = (ww == 7) ? ((pcq >= 4) ? 2 : 1) : 0;
          idq = rh * 3 + rw;
        }
        float vv[4];
        float mx = -1e30f;
        #pragma unroll
        for (int j = 0; j < 4; j++){
          int m = j * 16 + fr;
          int prk = m >> 3, pck = m & 7;
          float bi = bias_s[((prq - prk + 7) * 15 + (pcq - pck + 7)) * 8 + head];
          float v = sfr[i][j][rr] * scl + bi;
          if (SHIFT > 0){
            int rhk = (wh == 7) ? ((prk >= 4) ? 2 : 1) : 0;
            int rwk = (ww == 7) ? ((pck >= 4) ? 2 : 1) : 0;
            if (idq != rhk * 3 + rwk) v -= 100.f;
          }
          vv[j] = v;
          mx = fmaxf(mx, v);
        }
        for (int mm = 1; mm < 16; mm <<= 1) mx = fmaxf(mx, __shfl_xor(mx, mm, 64));
        float sum = 0.f;
        #pragma unroll
        for (int j = 0; j < 4; j++){ vv[j] = __expf(vv[j] - mx); sum += vv[j]; }
        for (int mm = 1; mm < 16; mm <<= 1) sum += __shfl_xor(sum, mm, 64);
        float inv = 1.0f / sum;
        #pragma unroll
        for (int j = 0; j < 4; j++) p_s[wave][rq][j * 16 + fr] = f2bf(vv[j] * inv);
      }
    }
    __syncthreads();   // p_s + vT_s visible

    // O = P(64x64) * V(64x32)
    f32x4 o[4][2];
    #pragma unroll
    for (int i = 0; i < 4; i++){ o[i][0] = z4; o[i][1] = z4; }
    #pragma unroll
    for (int ks = 0; ks < 2; ks++){
      bf16x8 pa[4], vb[2];
      #pragma unroll
      for (int i = 0; i < 4; i++) pa[i] = *(const bf16x8*)&p_s[wave][i * 16 + fr][ks * 32 + fq * 8];
      #pragma unroll
      for (int j = 0; j < 2; j++) vb[j] = *(const bf16x8*)&vT_s[wave][j * 16 + fr][ks * 32 + fq * 8];
      #pragma unroll
      for (int i = 0; i < 4; i++)
        #pragma unroll
        for (int j = 0; j < 2; j++)
          o[i][j] = __builtin_amdgcn_mfma_f32_16x16x32_bf16(pa[i], vb[j], o[i][j], 0, 0, 0);
    }
    // store: row rq -> token tmap[rq], channel = head*32 + j*16 + fr
    #pragma unroll
    for (int i = 0; i < 4; i++)
      #pragma unroll
      for (int j = 0; j < 2; j++)
        #pragma unroll
        for (int rr = 0; rr < 4; rr++){
          int rq = i * 16 + fq * 4 + rr;
          int t = tmap[rq];
          out[(size_t)t * 256 + head * 32 + j * 16 + fr] = f2bf(o[i][j][rr]);
        }
    __syncthreads();   // before next head overwrites LDS
  }
}

// ---------------- host ----------------
extern "C" void kernel_launch(void* const* d_in, const int* in_sizes, int n_in,
                              void* d_out, int out_size, void* d_ws, size_t ws_size,
                              hipStream_t stream){
  (void)in_sizes; (void)n_in; (void)out_size; (void)ws_size;
  const float* x      = (const float*)d_in[0];
  const float* cv1_w  = (const float*)d_in[1];
  const float* cv1_bn = (const float*)d_in[2];
  const float* cv2_w  = (const float*)d_in[3];
  const float* cv2_bn = (const float*)d_in[4];
  const float* cv3_w  = (const float*)d_in[5];
  const float* cv3_bn = (const float*)d_in[6];
  const float* n1g = (const float*)d_in[7];
  const float* n1b = (const float*)d_in[8];
  const float* qkvw = (const float*)d_in[9];
  const float* qkvb = (const float*)d_in[10];
  const float* pw  = (const float*)d_in[11];
  const float* pb  = (const float*)d_in[12];
  const float* rpb = (const float*)d_in[13];
  const float* n2g = (const float*)d_in[14];
  const float* n2b = (const float*)d_in[15];
  const float* f1w = (const float*)d_in[16];
  const float* f1b = (const float*)d_in[17];
  const float* f2w = (const float*)d_in[18];
  const float* f2b = (const float*)d_in[19];

  char* ws = (char*)d_ws;
  const size_t MB = 1024 * 1024;
  // layout (peak 360 MB):
  // [0,32)   ln_o / xT low / yF
  // [32,64)  at_o / xT high
  // [64,192) qkvB / hB
  // [192,256) yS fp32 residual stream
  // [256,320) x1 fp32
  // [320,328) wp bf16 weights
  // [328,360) y2 (cv2 out bf16)
  u16*   xT   = (u16*)(ws);
  u16*   ln_o = (u16*)(ws);
  u16*   yF   = (u16*)(ws);
  u16*   at_o = (u16*)(ws + 32 * MB);
  u16*   qkvB = (u16*)(ws + 64 * MB);
  u16*   hB   = qkvB;
  float* yS   = (float*)(ws + 192 * MB);
  float* x1   = (float*)(ws + 256 * MB);
  u16*   wp   = (u16*)(ws + 320 * MB);
  u16*   y2   = (u16*)(ws + 328 * MB);

  u16* wCv1 = wp;
  u16* wCv2 = wp + 131072;
  u16* wCv3 = wp + 262144;
  u16* wQkv = wp + 524288;
  u16* wPrj = wp + 917504;
  u16* wF1  = wp + 1048576;
  u16* wF2  = wp + 1572864;

  auto cvt = [&](const float* src, u16* dst, int n){
    int n4 = n >> 2;
    k_cvt<<<(n4 + 255) / 256, 256, 0, stream>>>(src, dst, n4);
  };
  cvt(cv1_w, wCv1, 131072);
  cvt(cv2_w, wCv2, 131072);
  cvt(cv3_w, wCv3, 262144);
  cvt(qkvw,  wQkv, 393216);
  cvt(pw,    wPrj, 131072);
  cvt(f1w,   wF1,  524288);
  cvt(f2w,   wF2,  524288);

  k_xpose<<<dim3(64, 8, 16), 256, 0, stream>>>(x, xT);

  const int M = 65536;
  auto gemm = [&](int mode, const u16* A, const u16* A2, const u16* W, int K, int N,
                  const float* bias, int bnN, const float* resid, int ldR,
                  float* outF, int ldF, u16* outB, int ldB, int colB){
    GemmP p{A, A2, W, K, N, bias, bnN, resid, ldR, outF, ldF, outB, ldB, colB};
    dim3 g(M / 128, N / 128);
    switch (mode){
      case 0: k_gemm<0><<<g, 256, 0, stream>>>(p); break;
      case 1: k_gemm<1><<<g, 256, 0, stream>>>(p); break;
      case 2: k_gemm<2><<<g, 256, 0, stream>>>(p); break;
      case 3: k_gemm<3><<<g, 256, 0, stream>>>(p); break;
      case 4: k_gemm<4><<<g, 256, 0, stream>>>(p); break;
      case 5: k_gemm<5><<<g, 256, 0, stream>>>(p); break;
      case 6: k_gemm<6><<<g, 256, 0, stream>>>(p); break;
    }
  };

  // cv1 -> yS (fp32 residual stream) ; cv2 -> y2 bf16
  gemm(0, xT, nullptr, wCv1, 512, 256, cv1_bn, 256, nullptr, 0, yS, 256, nullptr, 0, 0);
  gemm(1, xT, nullptr, wCv2, 512, 256, cv2_bn, 256, nullptr, 0, nullptr, 0, y2, 256, 0);

  for (int l = 0; l < 2; l++){
    k_ln<<<16384, 256, 0, stream>>>(yS, n1g + l * 256, n1b + l * 256, ln_o);
    gemm(2, ln_o, nullptr, wQkv + l * 196608, 256, 768, qkvb + l * 768, 0, nullptr, 0,
         nullptr, 0, qkvB, 768, 0);
    if (l == 0) k_attn<0><<<1024, 256, 0, stream>>>(qkvB, rpb, at_o);
    else        k_attn<4><<<1024, 256, 0, stream>>>(qkvB, rpb + 1800, at_o);
    gemm(3, at_o, nullptr, wPrj + l * 65536, 256, 256, pb + l * 256, 0, yS, 256,
         x1, 256, nullptr, 0, 0);
    k_ln<<<16384, 256, 0, stream>>>(x1, n2g + l * 256, n2b + l * 256, ln_o);
    gemm(4, ln_o, nullptr, wF1 + l * 262144, 256, 1024, f1b + l * 1024, 0, nullptr, 0,
         nullptr, 0, hB, 1024, 0);
    if (l == 0)
      gemm(3, hB, nullptr, wF2 + l * 262144, 1024, 256, f2b + l * 256, 0, x1, 256,
           yS, 256, nullptr, 0, 0);
    else
      gemm(5, hB, nullptr, wF2 + l * 262144, 1024, 256, f2b + l * 256, 0, x1, 256,
           yS, 256, yF, 256, 0);
  }

  // cv3: A = [yF | y2] (split at k=256) -> BN+SiLU -> d_out fp32 NCHW
  gemm(6, yF, y2, wCv3, 512, 512, cv3_bn, 512, nullptr, 0,
       (float*)d_out, 0, nullptr, 0, 0);
}

// Round 5
// 1326.650 us; speedup vs baseline: 1.2077x; 1.0623x over previous
//
#include <hip/hip_runtime.h>
#include <math.h>

using bf16x8 = __attribute__((ext_vector_type(8))) short;
using f32x4  = __attribute__((ext_vector_type(4))) float;
typedef unsigned short u16;

#define DI __device__ __forceinline__

DI u16 f2bf(float f){
  union { float f; unsigned u; } v; v.f = f;
  return (u16)((v.u + 0x7fffu + ((v.u >> 16) & 1u)) >> 16);
}

// async global->LDS, 16B per lane; LDS dest = wave-uniform base + lane*16
DI void gll16(const void* g, void* l){
  __builtin_amdgcn_global_load_lds((const __attribute__((address_space(1))) void*)g,
                                   (__attribute__((address_space(3))) void*)l, 16, 0, 0);
}

// ---------------- fp32 -> bf16 convert ----------------
__global__ void k_cvt(const float* __restrict__ in, u16* __restrict__ out, int n4){
  int i = blockIdx.x * 256 + threadIdx.x;
  if (i >= n4) return;
  float4 v = ((const float4*)in)[i];
  short4 o;
  o.x = (short)f2bf(v.x); o.y = (short)f2bf(v.y);
  o.z = (short)f2bf(v.z); o.w = (short)f2bf(v.w);
  ((short4*)out)[i] = o;
}

// ---------------- NCHW fp32 -> [token][C] bf16 transpose ----------------
__global__ void k_xpose(const float* __restrict__ x, u16* __restrict__ xT){
  __shared__ float tile[64][65];
  int hw0 = blockIdx.x * 64, c0 = blockIdx.y * 64, b = blockIdx.z;
  int tid = threadIdx.x;
  const float* src = x + ((size_t)(b * 512 + c0)) * 4096 + hw0;
  for (int rep = 0; rep < 16; rep++){
    int idx = rep * 256 + tid;
    int cc = idx >> 6, th = idx & 63;
    tile[cc][th] = src[(size_t)cc * 4096 + th];
  }
  __syncthreads();
  u16* dst = xT + ((size_t)(b * 4096 + hw0)) * 512 + c0;
  for (int rep = 0; rep < 16; rep++){
    int idx = rep * 256 + tid;
    int tt = idx >> 6, cc = idx & 63;
    dst[(size_t)tt * 512 + cc] = f2bf(tile[cc][tt]);
  }
}

// ---------------- LayerNorm (C=256), one wave per token ----------------
__global__ void k_ln(const float* __restrict__ xin, const float* __restrict__ g,
                     const float* __restrict__ bta, u16* __restrict__ out){
  int t = blockIdx.x * 4 + (threadIdx.x >> 6);
  int lane = threadIdx.x & 63;
  float4 v = ((const float4*)(xin + (size_t)t * 256))[lane];
  float s  = v.x + v.y + v.z + v.w;
  float s2 = v.x*v.x + v.y*v.y + v.z*v.z + v.w*v.w;
  for (int m = 1; m < 64; m <<= 1){ s += __shfl_xor(s, m, 64); s2 += __shfl_xor(s2, m, 64); }
  float mu  = s * (1.0f/256.0f);
  float var = s2 * (1.0f/256.0f) - mu*mu;
  float inv = rsqrtf(var + 1e-5f);
  float4 gg = ((const float4*)g)[lane];
  float4 bb = ((const float4*)bta)[lane];
  short4 o;
  o.x = (short)f2bf((v.x - mu) * inv * gg.x + bb.x);
  o.y = (short)f2bf((v.y - mu) * inv * gg.y + bb.y);
  o.z = (short)f2bf((v.z - mu) * inv * gg.z + bb.z);
  o.w = (short)f2bf((v.w - mu) * inv * gg.w + bb.w);
  ((short4*)(out + (size_t)t * 256))[lane] = o;
}

// ---------------- generic bf16 MFMA GEMM: C[M][N] = A[M][K] * W[N][K]^T ----------------
// BK=64, global_load_lds staging, XOR chunk-swizzle, double-buffered LDS with
// counted vmcnt (tile t+1 in flight across barriers), chunked XCD grid swizzle.
// MODE 0: BN+SiLU -> fp32 out             (cv1)
// MODE 1: BN+SiLU -> bf16 out             (cv2)
// MODE 2: +bias   -> bf16 out             (qkv)
// MODE 3: +bias +resid -> fp32 out        (proj, fc2 l0)
// MODE 4: +bias GELU -> bf16 out          (fc1)
// MODE 5: +bias +resid -> fp32 + bf16 dual(fc2 l1)
// MODE 6: split-A (A:k<256, A2:k>=256, ld 256 each); BN+SiLU -> fp32 NCHW d_out
struct GemmP {
  const u16* A; const u16* A2; const u16* W;
  int K; int N; int NB;                 // NB = N/128 (n-blocks, fastest grid dim)
  const float* bias;                    // bias, or BN params (4 rows of bnN)
  int bnN;
  const float* resid; int ldR;
  float* outF; int ldF;
  u16* outB; int ldB; int colB;
};

template<int MODE>
__launch_bounds__(256)
__global__ void k_gemm(GemmP p){
  __shared__ __align__(16) u16 sA[2][128 * 64];   // 2 x 16 KB
  __shared__ __align__(16) u16 sB[2][128 * 64];   // 2 x 16 KB
  __shared__ float sT[(MODE == 6) ? 32 * 136 : 1];
  int tid = threadIdx.x;
  int wave = tid >> 6, lane = tid & 63;
  int fq = lane >> 4, fr = lane & 15;

  // chunked XCD swizzle: hw bid -> logical lid so each XCD owns a contiguous
  // chunk of (m-major, n-fastest) blocks; consecutive blocks share the A-tile.
  int nwg = gridDim.x;
  int bid = blockIdx.x;
  int lid = (bid & 7) * (nwg >> 3) + (bid >> 3);
  int m0 = (lid / p.NB) * 128, n0 = (lid % p.NB) * 128;

  int wm = (wave >> 1) * 64, wn = (wave & 1) * 64;
  const int K = p.K;

  // staging geometry: lane covers (row = l>>3, chunk = l&7), XOR-swizzled source
  int rsub = lane >> 3;
  int gk   = ((lane & 7) ^ rsub) << 3;

  auto STAGE = [&](int k0, int c){
    #pragma unroll
    for (int it = 0; it < 4; it++){
      int row = (it * 4 + wave) * 8 + rsub;
      const u16* ga;
      if constexpr (MODE == 6){
        const u16* base = (k0 < 256) ? p.A : p.A2;
        ga = base + (size_t)(m0 + row) * 256 + (k0 & 255) + gk;
      } else {
        ga = p.A + (size_t)(m0 + row) * K + k0 + gk;
      }
      gll16(ga, &sA[c][(it * 4 + wave) * 512]);
      gll16(p.W + (size_t)(n0 + row) * K + k0 + gk, &sB[c][(it * 4 + wave) * 512]);
    }
  };

  f32x4 acc[4][4];
  f32x4 z4 = {0.f, 0.f, 0.f, 0.f};
  #pragma unroll
  for (int i = 0; i < 4; i++)
    #pragma unroll
    for (int j = 0; j < 4; j++) acc[i][j] = z4;

  STAGE(0, 0);
  int c = 0;
  for (int k0 = 0; k0 < K; k0 += 64){
    bool last = (k0 + 64 >= K);
    if (!last) STAGE(k0 + 64, c ^ 1);
    if (last) asm volatile("s_waitcnt vmcnt(0)" ::: "memory");
    else      asm volatile("s_waitcnt vmcnt(8)" ::: "memory");
    __builtin_amdgcn_s_barrier();
    #pragma unroll
    for (int kk = 0; kk < 2; kk++){
      bf16x8 af[4], bfr[4];
      #pragma unroll
      for (int i = 0; i < 4; i++){
        int r = wm + i * 16 + fr;
        af[i] = *(const bf16x8*)(&sA[c][r * 64 + ((((kk << 2) + fq) ^ (fr & 7)) << 3)]);
      }
      #pragma unroll
      for (int j = 0; j < 4; j++){
        int r = wn + j * 16 + fr;
        bfr[j] = *(const bf16x8*)(&sB[c][r * 64 + ((((kk << 2) + fq) ^ (fr & 7)) << 3)]);
      }
      #pragma unroll
      for (int i = 0; i < 4; i++)
        #pragma unroll
        for (int j = 0; j < 4; j++)
          acc[i][j] = __builtin_amdgcn_mfma_f32_16x16x32_bf16(af[i], bfr[j], acc[i][j], 0, 0, 0);
    }
    __builtin_amdgcn_s_barrier();
    c ^= 1;
  }

  if constexpr (MODE != 6){
    #pragma unroll
    for (int j = 0; j < 4; j++){
      int col = n0 + wn + j * 16 + fr;
      float sc = 0.f, sh = 0.f;
      if constexpr (MODE == 0 || MODE == 1){
        float gg = p.bias[col];
        float bb = p.bias[p.bnN + col];
        float mv = p.bias[2 * p.bnN + col];
        float vv = p.bias[3 * p.bnN + col];
        sc = gg * rsqrtf(vv + 1e-5f);
        sh = bb - mv * sc;
      } else {
        sh = p.bias[col];
      }
      #pragma unroll
      for (int i = 0; i < 4; i++){
        #pragma unroll
        for (int rr = 0; rr < 4; rr++){
          int row = m0 + wm + i * 16 + fq * 4 + rr;
          float v = acc[i][j][rr];
          if constexpr (MODE == 0 || MODE == 1){ v = v * sc + sh; v = v / (1.f + __expf(-v)); }
          else v += sh;
          if constexpr (MODE == 3 || MODE == 5) v += p.resid[(size_t)row * p.ldR + col];
          if constexpr (MODE == 4) v = 0.5f * v * (1.f + erff(v * 0.70710678118f));
          if constexpr (MODE == 0 || MODE == 3 || MODE == 5) p.outF[(size_t)row * p.ldF + col] = v;
          if constexpr (MODE == 1 || MODE == 2 || MODE == 4 || MODE == 5)
            p.outB[(size_t)row * p.ldB + p.colB + col] = f2bf(v);
        }
      }
    }
  } else {
    // BN+SiLU then fp32 NCHW store via LDS transpose (4 passes of 32 channels)
    int b = m0 >> 12;
    int hw0 = m0 & 4095;
    #pragma unroll
    for (int ps = 0; ps < 4; ps++){
      if (wn == (ps >> 1) * 64){
        #pragma unroll
        for (int jj = 0; jj < 2; jj++){
          int j = (ps & 1) * 2 + jj;
          int col = n0 + wn + j * 16 + fr;
          float gg = p.bias[col];
          float bb = p.bias[p.bnN + col];
          float mv = p.bias[2 * p.bnN + col];
          float vv = p.bias[3 * p.bnN + col];
          float sc = gg * rsqrtf(vv + 1e-5f);
          float sh = bb - mv * sc;
          int nl = wn + j * 16 + fr - ps * 32;
          #pragma unroll
          for (int i = 0; i < 4; i++)
            #pragma unroll
            for (int rr = 0; rr < 4; rr++){
              float v = acc[i][j][rr];
              v = v * sc + sh; v = v / (1.f + __expf(-v));
              sT[nl * 136 + wm + i * 16 + fq * 4 + rr] = v;
            }
        }
      }
      __syncthreads();
      for (int rep = 0; rep < 16; rep++){
        int flat = rep * 256 + tid;
        int nl = flat >> 7, ml = flat & 127;
        int cch = n0 + ps * 32 + nl;
        p.outF[((size_t)(b * 512 + cch)) * 4096 + hw0 + ml] = sT[nl * 136 + ml];
      }
      __syncthreads();
    }
  }
}

// ---------------- windowed attention: one block per window, 4 waves x 2 heads ----------------
template<int SHIFT>
__launch_bounds__(256)
__global__ void k_attn(const u16* __restrict__ qkv, const float* __restrict__ rpb,
                       u16* __restrict__ out){
  __shared__ int tmap[64];
  __shared__ float bias_s[1800];
  __shared__ __align__(16) u16 p_s[4][64][72];
  __shared__ __align__(16) u16 vT_s[4][32][72];
  int tid = threadIdx.x, wave = tid >> 6, lane = tid & 63;
  int fq = lane >> 4, fr = lane & 15;
  int wi = blockIdx.x;
  int b = wi >> 6, wh = (wi >> 3) & 7, ww = wi & 7;

  for (int i = tid; i < 1800; i += 256) bias_s[i] = rpb[i];
  if (tid < 64){
    int r = tid >> 3, c = tid & 7;
    int h = (wh * 8 + r + SHIFT) & 63;
    int w = (ww * 8 + c + SHIFT) & 63;
    tmap[tid] = (b << 12) | (h << 6) | w;
  }
  __syncthreads();

  const float scl = 0.17677669529663687f;  // 1/sqrt(32)
  for (int hh = 0; hh < 2; hh++){
    int head = wave * 2 + hh;

    // stage V^T for this head (rows=dim, cols=token)
    {
      const u16* vrow = qkv + (size_t)tmap[lane] * 768 + 512 + head * 32;
      #pragma unroll
      for (int cg = 0; cg < 4; cg++){
        bf16x8 vv = *(const bf16x8*)(vrow + cg * 8);
        #pragma unroll
        for (int e = 0; e < 8; e++) vT_s[wave][cg * 8 + e][lane] = (u16)vv[e];
      }
    }

    // QK^T (K-dim = 32 -> one mfma step per 16x16 fragment)
    bf16x8 qf[4], kf[4];
    #pragma unroll
    for (int i = 0; i < 4; i++){
      int n = i * 16 + fr;
      size_t base = (size_t)tmap[n] * 768 + head * 32 + fq * 8;
      qf[i] = *(const bf16x8*)(qkv + base);
      kf[i] = *(const bf16x8*)(qkv + base + 256);
    }
    f32x4 z4 = {0.f, 0.f, 0.f, 0.f};
    f32x4 sfr[4][4];
    #pragma unroll
    for (int i = 0; i < 4; i++)
      #pragma unroll
      for (int j = 0; j < 4; j++) sfr[i][j] = z4;
    #pragma unroll
    for (int i = 0; i < 4; i++)
      #pragma unroll
      for (int j = 0; j < 4; j++)
        sfr[i][j] = __builtin_amdgcn_mfma_f32_16x16x32_bf16(qf[i], kf[j], sfr[i][j], 0, 0, 0);

    // softmax rows: row rq = i*16 + fq*4 + rr ; cols j*16 + fr ; reduce over 16 lanes (fr)
    #pragma unroll
    for (int i = 0; i < 4; i++){
      #pragma unroll
      for (int rr = 0; rr < 4; rr++){
        int rq = i * 16 + fq * 4 + rr;
        int prq = rq >> 3, pcq = rq & 7;
        int idq = 0;
        if (SHIFT > 0){
          int rh = (wh == 7) ? ((prq >= 4) ? 2 : 1) : 0;
          int rw = (ww == 7) ? ((pcq >= 4) ? 2 : 1) : 0;
          idq = rh * 3 + rw;
        }
        float vv[4];
        float mx = -1e30f;
        #pragma unroll
        for (int j = 0; j < 4; j++){
          int m = j * 16 + fr;
          int prk = m >> 3, pck = m & 7;
          float bi = bias_s[((prq - prk + 7) * 15 + (pcq - pck + 7)) * 8 + head];
          float v = sfr[i][j][rr] * scl + bi;
          if (SHIFT > 0){
            int rhk = (wh == 7) ? ((prk >= 4) ? 2 : 1) : 0;
            int rwk = (ww == 7) ? ((pck >= 4) ? 2 : 1) : 0;
            if (idq != rhk * 3 + rwk) v -= 100.f;
          }
          vv[j] = v;
          mx = fmaxf(mx, v);
        }
        for (int mm = 1; mm < 16; mm <<= 1) mx = fmaxf(mx, __shfl_xor(mx, mm, 64));
        float sum = 0.f;
        #pragma unroll
        for (int j = 0; j < 4; j++){ vv[j] = __expf(vv[j] - mx); sum += vv[j]; }
        for (int mm = 1; mm < 16; mm <<= 1) sum += __shfl_xor(sum, mm, 64);
        float inv = 1.0f / sum;
        #pragma unroll
        for (int j = 0; j < 4; j++) p_s[wave][rq][j * 16 + fr] = f2bf(vv[j] * inv);
      }
    }
    __syncthreads();   // p_s + vT_s visible

    // O = P(64x64) * V(64x32)
    f32x4 o[4][2];
    #pragma unroll
    for (int i = 0; i < 4; i++){ o[i][0] = z4; o[i][1] = z4; }
    #pragma unroll
    for (int ks = 0; ks < 2; ks++){
      bf16x8 pa[4], vb[2];
      #pragma unroll
      for (int i = 0; i < 4; i++) pa[i] = *(const bf16x8*)&p_s[wave][i * 16 + fr][ks * 32 + fq * 8];
      #pragma unroll
      for (int j = 0; j < 2; j++) vb[j] = *(const bf16x8*)&vT_s[wave][j * 16 + fr][ks * 32 + fq * 8];
      #pragma unroll
      for (int i = 0; i < 4; i++)
        #pragma unroll
        for (int j = 0; j < 2; j++)
          o[i][j] = __builtin_amdgcn_mfma_f32_16x16x32_bf16(pa[i], vb[j], o[i][j], 0, 0, 0);
    }
    // store: row rq -> token tmap[rq], channel = head*32 + j*16 + fr
    #pragma unroll
    for (int i = 0; i < 4; i++)
      #pragma unroll
      for (int j = 0; j < 2; j++)
        #pragma unroll
        for (int rr = 0; rr < 4; rr++){
          int rq = i * 16 + fq * 4 + rr;
          int t = tmap[rq];
          out[(size_t)t * 256 + head * 32 + j * 16 + fr] = f2bf(o[i][j][rr]);
        }
    __syncthreads();   // before next head overwrites LDS
  }
}

// ---------------- host ----------------
extern "C" void kernel_launch(void* const* d_in, const int* in_sizes, int n_in,
                              void* d_out, int out_size, void* d_ws, size_t ws_size,
                              hipStream_t stream){
  (void)in_sizes; (void)n_in; (void)out_size; (void)ws_size;
  const float* x      = (const float*)d_in[0];
  const float* cv1_w  = (const float*)d_in[1];
  const float* cv1_bn = (const float*)d_in[2];
  const float* cv2_w  = (const float*)d_in[3];
  const float* cv2_bn = (const float*)d_in[4];
  const float* cv3_w  = (const float*)d_in[5];
  const float* cv3_bn = (const float*)d_in[6];
  const float* n1g = (const float*)d_in[7];
  const float* n1b = (const float*)d_in[8];
  const float* qkvw = (const float*)d_in[9];
  const float* qkvb = (const float*)d_in[10];
  const float* pw  = (const float*)d_in[11];
  const float* pb  = (const float*)d_in[12];
  const float* rpb = (const float*)d_in[13];
  const float* n2g = (const float*)d_in[14];
  const float* n2b = (const float*)d_in[15];
  const float* f1w = (const float*)d_in[16];
  const float* f1b = (const float*)d_in[17];
  const float* f2w = (const float*)d_in[18];
  const float* f2b = (const float*)d_in[19];

  char* ws = (char*)d_ws;
  const size_t MB = 1024 * 1024;
  // layout (peak 360 MB):
  // [0,32)   ln_o / xT low / yF
  // [32,64)  at_o / xT high
  // [64,192) qkvB / hB
  // [192,256) yS fp32 residual stream
  // [256,320) x1 fp32
  // [320,328) wp bf16 weights
  // [328,360) y2 (cv2 out bf16)
  u16*   xT   = (u16*)(ws);
  u16*   ln_o = (u16*)(ws);
  u16*   yF   = (u16*)(ws);
  u16*   at_o = (u16*)(ws + 32 * MB);
  u16*   qkvB = (u16*)(ws + 64 * MB);
  u16*   hB   = qkvB;
  float* yS   = (float*)(ws + 192 * MB);
  float* x1   = (float*)(ws + 256 * MB);
  u16*   wp   = (u16*)(ws + 320 * MB);
  u16*   y2   = (u16*)(ws + 328 * MB);

  u16* wCv1 = wp;
  u16* wCv2 = wp + 131072;
  u16* wCv3 = wp + 262144;
  u16* wQkv = wp + 524288;
  u16* wPrj = wp + 917504;
  u16* wF1  = wp + 1048576;
  u16* wF2  = wp + 1572864;

  auto cvt = [&](const float* src, u16* dst, int n){
    int n4 = n >> 2;
    k_cvt<<<(n4 + 255) / 256, 256, 0, stream>>>(src, dst, n4);
  };
  cvt(cv1_w, wCv1, 131072);
  cvt(cv2_w, wCv2, 131072);
  cvt(cv3_w, wCv3, 262144);
  cvt(qkvw,  wQkv, 393216);
  cvt(pw,    wPrj, 131072);
  cvt(f1w,   wF1,  524288);
  cvt(f2w,   wF2,  524288);

  k_xpose<<<dim3(64, 8, 16), 256, 0, stream>>>(x, xT);

  const int M = 65536;
  auto gemm = [&](int mode, const u16* A, const u16* A2, const u16* W, int K, int N,
                  const float* bias, int bnN, const float* resid, int ldR,
                  float* outF, int ldF, u16* outB, int ldB, int colB){
    int NB = N / 128;
    GemmP p{A, A2, W, K, N, NB, bias, bnN, resid, ldR, outF, ldF, outB, ldB, colB};
    int nwg = (M / 128) * NB;
    switch (mode){
      case 0: k_gemm<0><<<nwg, 256, 0, stream>>>(p); break;
      case 1: k_gemm<1><<<nwg, 256, 0, stream>>>(p); break;
      case 2: k_gemm<2><<<nwg, 256, 0, stream>>>(p); break;
      case 3: k_gemm<3><<<nwg, 256, 0, stream>>>(p); break;
      case 4: k_gemm<4><<<nwg, 256, 0, stream>>>(p); break;
      case 5: k_gemm<5><<<nwg, 256, 0, stream>>>(p); break;
      case 6: k_gemm<6><<<nwg, 256, 0, stream>>>(p); break;
    }
  };

  // cv1 -> yS (fp32 residual stream) ; cv2 -> y2 bf16
  gemm(0, xT, nullptr, wCv1, 512, 256, cv1_bn, 256, nullptr, 0, yS, 256, nullptr, 0, 0);
  gemm(1, xT, nullptr, wCv2, 512, 256, cv2_bn, 256, nullptr, 0, nullptr, 0, y2, 256, 0);

  for (int l = 0; l < 2; l++){
    k_ln<<<16384, 256, 0, stream>>>(yS, n1g + l * 256, n1b + l * 256, ln_o);
    gemm(2, ln_o, nullptr, wQkv + l * 196608, 256, 768, qkvb + l * 768, 0, nullptr, 0,
         nullptr, 0, qkvB, 768, 0);
    if (l == 0) k_attn<0><<<1024, 256, 0, stream>>>(qkvB, rpb, at_o);
    else        k_attn<4><<<1024, 256, 0, stream>>>(qkvB, rpb + 1800, at_o);
    gemm(3, at_o, nullptr, wPrj + l * 65536, 256, 256, pb + l * 256, 0, yS, 256,
         x1, 256, nullptr, 0, 0);
    k_ln<<<16384, 256, 0, stream>>>(x1, n2g + l * 256, n2b + l * 256, ln_o);
    gemm(4, ln_o, nullptr, wF1 + l * 262144, 256, 1024, f1b + l * 1024, 0, nullptr, 0,
         nullptr, 0, hB, 1024, 0);
    if (l == 0)
      gemm(3, hB, nullptr, wF2 + l * 262144, 1024, 256, f2b + l * 256, 0, x1, 256,
           yS, 256, nullptr, 0, 0);
    else
      gemm(5, hB, nullptr, wF2 + l * 262144, 1024, 256, f2b + l * 256, 0, x1, 256,
           yS, 256, yF, 256, 0);
  }

  // cv3: A = [yF | y2] (split at k=256) -> BN+SiLU -> d_out fp32 NCHW
  gemm(6, yF, y2, wCv3, 512, 512, cv3_bn, 512, nullptr, 0,
       (float*)d_out, 0, nullptr, 0, 0);
}

// Round 6
// 1212.050 us; speedup vs baseline: 1.3219x; 1.0946x over previous
//
#include <hip/hip_runtime.h>
#include <math.h>

using bf16x8 = __attribute__((ext_vector_type(8))) short;
using f32x4  = __attribute__((ext_vector_type(4))) float;
typedef unsigned short u16;

#define DI __device__ __forceinline__

DI u16 f2bf(float f){
  union { float f; unsigned u; } v; v.f = f;
  return (u16)((v.u + 0x7fffu + ((v.u >> 16) & 1u)) >> 16);
}

// async global->LDS, 16B per lane; LDS dest = wave-uniform base + lane*16
DI void gll16(const void* g, void* l){
  __builtin_amdgcn_global_load_lds((const __attribute__((address_space(1))) void*)g,
                                   (__attribute__((address_space(3))) void*)l, 16, 0, 0);
}

// ---------------- batched fp32 -> bf16 convert (7 weight tensors, 1 launch) ----
struct CvtP {
  const float* src[7];
  u16* dst[7];
  int cum[8];    // cumulative sizes in float4 units
};
__global__ void k_cvt7(CvtP p){
  int gid = blockIdx.x * 256 + threadIdx.x;
  if (gid >= p.cum[7]) return;
  int s = 0;
  #pragma unroll
  for (int t = 0; t < 7; t++) if (gid >= p.cum[t + 1]) s = t + 1;
  int i = gid - p.cum[s];
  float4 v = ((const float4*)p.src[s])[i];
  short4 o;
  o.x = (short)f2bf(v.x); o.y = (short)f2bf(v.y);
  o.z = (short)f2bf(v.z); o.w = (short)f2bf(v.w);
  ((short4*)p.dst[s])[i] = o;
}

// ---------------- NCHW fp32 -> [token][C] bf16 transpose ----------------
__global__ void k_xpose(const float* __restrict__ x, u16* __restrict__ xT){
  __shared__ float tile[64][65];
  int hw0 = blockIdx.x * 64, c0 = blockIdx.y * 64, b = blockIdx.z;
  int tid = threadIdx.x;
  const float* src = x + ((size_t)(b * 512 + c0)) * 4096 + hw0;
  for (int rep = 0; rep < 16; rep++){
    int idx = rep * 256 + tid;
    int cc = idx >> 6, th = idx & 63;
    tile[cc][th] = src[(size_t)cc * 4096 + th];
  }
  __syncthreads();
  u16* dst = xT + ((size_t)(b * 4096 + hw0)) * 512 + c0;
  for (int rep = 0; rep < 16; rep++){
    int idx = rep * 256 + tid;
    int tt = idx >> 6, cc = idx & 63;
    dst[(size_t)tt * 512 + cc] = f2bf(tile[cc][tt]);
  }
}

// ---------------- LayerNorm (C=256), one wave per token ----------------
__global__ void k_ln(const float* __restrict__ xin, const float* __restrict__ g,
                     const float* __restrict__ bta, u16* __restrict__ out){
  int t = blockIdx.x * 4 + (threadIdx.x >> 6);
  int lane = threadIdx.x & 63;
  float4 v = ((const float4*)(xin + (size_t)t * 256))[lane];
  float s  = v.x + v.y + v.z + v.w;
  float s2 = v.x*v.x + v.y*v.y + v.z*v.z + v.w*v.w;
  for (int m = 1; m < 64; m <<= 1){ s += __shfl_xor(s, m, 64); s2 += __shfl_xor(s2, m, 64); }
  float mu  = s * (1.0f/256.0f);
  float var = s2 * (1.0f/256.0f) - mu*mu;
  float inv = rsqrtf(var + 1e-5f);
  float4 gg = ((const float4*)g)[lane];
  float4 bb = ((const float4*)bta)[lane];
  short4 o;
  o.x = (short)f2bf((v.x - mu) * inv * gg.x + bb.x);
  o.y = (short)f2bf((v.y - mu) * inv * gg.y + bb.y);
  o.z = (short)f2bf((v.z - mu) * inv * gg.z + bb.z);
  o.w = (short)f2bf((v.w - mu) * inv * gg.w + bb.w);
  ((short4*)(out + (size_t)t * 256))[lane] = o;
}

// ---------------- generic bf16 MFMA GEMM: C[M][N] = A[M][K] * W[N][K]^T ----------------
// BK=64, global_load_lds staging, XOR chunk-swizzle, double-buffered LDS with
// counted vmcnt (tile t+1 in flight across barriers), chunked XCD grid swizzle.
// MODE 0: BN+SiLU -> fp32 out             (cv1)
// MODE 1: BN+SiLU -> bf16 out             (cv2)
// MODE 2: +bias   -> bf16 out             (qkv)
// MODE 3: +bias +resid -> fp32 out        (proj, fc2 l0)
// MODE 4: +bias GELU -> bf16 out          (fc1)
// MODE 5: +bias +resid -> fp32 + bf16 dual(fc2 l1)
// MODE 6: split-A (A:k<256, A2:k>=256, ld 256 each); BN+SiLU -> fp32 NCHW d_out,
//         transpose epilogue reuses the (dead) sA/sB LDS after the K-loop.
struct GemmP {
  const u16* A; const u16* A2; const u16* W;
  int K; int N; int NB;                 // NB = N/128 (n-blocks, fastest grid dim)
  const float* bias;                    // bias, or BN params (4 rows of bnN)
  int bnN;
  const float* resid; int ldR;
  float* outF; int ldF;
  u16* outB; int ldB; int colB;
};

template<int MODE>
__launch_bounds__(256)
__global__ void k_gemm(GemmP p){
  // smem[0..1] = A double-buffer, smem[2..3] = B double-buffer (16 KB each).
  // MODE 6 reuses the whole 64 KB as a float transpose buffer after the K-loop.
  __shared__ __align__(16) u16 smem[4][128 * 64];
  int tid = threadIdx.x;
  int wave = tid >> 6, lane = tid & 63;
  int fq = lane >> 4, fr = lane & 15;

  // chunked XCD swizzle: hw bid -> logical lid so each XCD owns a contiguous
  // chunk of (m-major, n-fastest) blocks; consecutive blocks share the A-tile.
  int nwg = gridDim.x;
  int bid = blockIdx.x;
  int lid = (bid & 7) * (nwg >> 3) + (bid >> 3);
  int m0 = (lid / p.NB) * 128, n0 = (lid % p.NB) * 128;

  int wm = (wave >> 1) * 64, wn = (wave & 1) * 64;
  const int K = p.K;

  // staging geometry: lane covers (row = l>>3, chunk = l&7), XOR-swizzled source
  int rsub = lane >> 3;
  int gk   = ((lane & 7) ^ rsub) << 3;

  auto STAGE = [&](int k0, int c){
    #pragma unroll
    for (int it = 0; it < 4; it++){
      int row = (it * 4 + wave) * 8 + rsub;
      const u16* ga;
      if constexpr (MODE == 6){
        const u16* base = (k0 < 256) ? p.A : p.A2;
        ga = base + (size_t)(m0 + row) * 256 + (k0 & 255) + gk;
      } else {
        ga = p.A + (size_t)(m0 + row) * K + k0 + gk;
      }
      gll16(ga, &smem[c][(it * 4 + wave) * 512]);
      gll16(p.W + (size_t)(n0 + row) * K + k0 + gk, &smem[2 + c][(it * 4 + wave) * 512]);
    }
  };

  f32x4 acc[4][4];
  f32x4 z4 = {0.f, 0.f, 0.f, 0.f};
  #pragma unroll
  for (int i = 0; i < 4; i++)
    #pragma unroll
    for (int j = 0; j < 4; j++) acc[i][j] = z4;

  STAGE(0, 0);
  int c = 0;
  for (int k0 = 0; k0 < K; k0 += 64){
    bool last = (k0 + 64 >= K);
    if (!last) STAGE(k0 + 64, c ^ 1);
    if (last) asm volatile("s_waitcnt vmcnt(0)" ::: "memory");
    else      asm volatile("s_waitcnt vmcnt(8)" ::: "memory");
    __builtin_amdgcn_s_barrier();
    #pragma unroll
    for (int kk = 0; kk < 2; kk++){
      bf16x8 af[4], bfr[4];
      #pragma unroll
      for (int i = 0; i < 4; i++){
        int r = wm + i * 16 + fr;
        af[i] = *(const bf16x8*)(&smem[c][r * 64 + ((((kk << 2) + fq) ^ (fr & 7)) << 3)]);
      }
      #pragma unroll
      for (int j = 0; j < 4; j++){
        int r = wn + j * 16 + fr;
        bfr[j] = *(const bf16x8*)(&smem[2 + c][r * 64 + ((((kk << 2) + fq) ^ (fr & 7)) << 3)]);
      }
      #pragma unroll
      for (int i = 0; i < 4; i++)
        #pragma unroll
        for (int j = 0; j < 4; j++)
          acc[i][j] = __builtin_amdgcn_mfma_f32_16x16x32_bf16(af[i], bfr[j], acc[i][j], 0, 0, 0);
    }
    __builtin_amdgcn_s_barrier();
    c ^= 1;
  }

  if constexpr (MODE != 6){
    #pragma unroll
    for (int j = 0; j < 4; j++){
      int col = n0 + wn + j * 16 + fr;
      float sc = 0.f, sh = 0.f;
      if constexpr (MODE == 0 || MODE == 1){
        float gg = p.bias[col];
        float bb = p.bias[p.bnN + col];
        float mv = p.bias[2 * p.bnN + col];
        float vv = p.bias[3 * p.bnN + col];
        sc = gg * rsqrtf(vv + 1e-5f);
        sh = bb - mv * sc;
      } else {
        sh = p.bias[col];
      }
      #pragma unroll
      for (int i = 0; i < 4; i++){
        #pragma unroll
        for (int rr = 0; rr < 4; rr++){
          int row = m0 + wm + i * 16 + fq * 4 + rr;
          float v = acc[i][j][rr];
          if constexpr (MODE == 0 || MODE == 1){ v = v * sc + sh; v = v / (1.f + __expf(-v)); }
          else v += sh;
          if constexpr (MODE == 3 || MODE == 5) v += p.resid[(size_t)row * p.ldR + col];
          if constexpr (MODE == 4) v = 0.5f * v * (1.f + erff(v * 0.70710678118f));
          if constexpr (MODE == 0 || MODE == 3 || MODE == 5) p.outF[(size_t)row * p.ldF + col] = v;
          if constexpr (MODE == 1 || MODE == 2 || MODE == 4 || MODE == 5)
            p.outB[(size_t)row * p.ldB + p.colB + col] = f2bf(v);
        }
      }
    }
  } else {
    // BN+SiLU then fp32 NCHW store via LDS transpose.
    // 2 passes x 64 channels; sT = reused sA/sB space, stride 137 (conflict-free).
    float* sT = (float*)smem;           // 16384 floats available, need 64*137=8768
    int b = m0 >> 12;
    int hw0 = m0 & 4095;
    #pragma unroll
    for (int ps = 0; ps < 2; ps++){
      if (wn == ps * 64){
        #pragma unroll
        for (int j = 0; j < 4; j++){
          int col = n0 + wn + j * 16 + fr;
          float gg = p.bias[col];
          float bb = p.bias[p.bnN + col];
          float mv = p.bias[2 * p.bnN + col];
          float vv = p.bias[3 * p.bnN + col];
          float sc = gg * rsqrtf(vv + 1e-5f);
          float sh = bb - mv * sc;
          int nl = j * 16 + fr;           // 0..63 channel within pass
          #pragma unroll
          for (int i = 0; i < 4; i++)
            #pragma unroll
            for (int rr = 0; rr < 4; rr++){
              float v = acc[i][j][rr];
              v = v * sc + sh; v = v / (1.f + __expf(-v));
              sT[nl * 137 + wm + i * 16 + fq * 4 + rr] = v;
            }
        }
      }
      __syncthreads();
      // read back + store: 64 ch x 128 hw = 2048 float4s, 8 iters x 256 threads
      #pragma unroll
      for (int it = 0; it < 8; it++){
        int flat4 = it * 256 + tid;
        int nl = flat4 >> 5, m4 = flat4 & 31;
        float4 v4 = *(const float4*)&sT[nl * 137 + m4 * 4];
        int cch = n0 + ps * 64 + nl;
        *(float4*)&p.outF[((size_t)(b * 512 + cch)) * 4096 + hw0 + m4 * 4] = v4;
      }
      __syncthreads();
    }
  }
}

// ---------------- windowed attention: one block per window, 4 waves x 2 heads ----------------
template<int SHIFT>
__launch_bounds__(256)
__global__ void k_attn(const u16* __restrict__ qkv, const float* __restrict__ rpb,
                       u16* __restrict__ out){
  __shared__ int tmap[64];
  __shared__ float bias_s[1800];
  __shared__ __align__(16) u16 p_s[4][64][72];
  __shared__ __align__(16) u16 vT_s[4][32][72];
  int tid = threadIdx.x, wave = tid >> 6, lane = tid & 63;
  int fq = lane >> 4, fr = lane & 15;
  int wi = blockIdx.x;
  int b = wi >> 6, wh = (wi >> 3) & 7, ww = wi & 7;

  for (int i = tid; i < 1800; i += 256) bias_s[i] = rpb[i];
  if (tid < 64){
    int r = tid >> 3, c = tid & 7;
    int h = (wh * 8 + r + SHIFT) & 63;
    int w = (ww * 8 + c + SHIFT) & 63;
    tmap[tid] = (b << 12) | (h << 6) | w;
  }
  __syncthreads();

  const float scl = 0.17677669529663687f;  // 1/sqrt(32)
  for (int hh = 0; hh < 2; hh++){
    int head = wave * 2 + hh;

    // stage V^T for this head (rows=dim, cols=token)
    {
      const u16* vrow = qkv + (size_t)tmap[lane] * 768 + 512 + head * 32;
      #pragma unroll
      for (int cg = 0; cg < 4; cg++){
        bf16x8 vv = *(const bf16x8*)(vrow + cg * 8);
        #pragma unroll
        for (int e = 0; e < 8; e++) vT_s[wave][cg * 8 + e][lane] = (u16)vv[e];
      }
    }

    // QK^T (K-dim = 32 -> one mfma step per 16x16 fragment)
    bf16x8 qf[4], kf[4];
    #pragma unroll
    for (int i = 0; i < 4; i++){
      int n = i * 16 + fr;
      size_t base = (size_t)tmap[n] * 768 + head * 32 + fq * 8;
      qf[i] = *(const bf16x8*)(qkv + base);
      kf[i] = *(const bf16x8*)(qkv + base + 256);
    }
    f32x4 z4 = {0.f, 0.f, 0.f, 0.f};
    f32x4 sfr[4][4];
    #pragma unroll
    for (int i = 0; i < 4; i++)
      #pragma unroll
      for (int j = 0; j < 4; j++) sfr[i][j] = z4;
    #pragma unroll
    for (int i = 0; i < 4; i++)
      #pragma unroll
      for (int j = 0; j < 4; j++)
        sfr[i][j] = __builtin_amdgcn_mfma_f32_16x16x32_bf16(qf[i], kf[j], sfr[i][j], 0, 0, 0);

    // softmax rows: row rq = i*16 + fq*4 + rr ; cols j*16 + fr ; reduce over 16 lanes (fr)
    #pragma unroll
    for (int i = 0; i < 4; i++){
      #pragma unroll
      for (int rr = 0; rr < 4; rr++){
        int rq = i * 16 + fq * 4 + rr;
        int prq = rq >> 3, pcq = rq & 7;
        int idq = 0;
        if (SHIFT > 0){
          int rh = (wh == 7) ? ((prq >= 4) ? 2 : 1) : 0;
          int rw = (ww == 7) ? ((pcq >= 4) ? 2 : 1) : 0;
          idq = rh * 3 + rw;
        }
        float vv[4];
        float mx = -1e30f;
        #pragma unroll
        for (int j = 0; j < 4; j++){
          int m = j * 16 + fr;
          int prk = m >> 3, pck = m & 7;
          float bi = bias_s[((prq - prk + 7) * 15 + (pcq - pck + 7)) * 8 + head];
          float v = sfr[i][j][rr] * scl + bi;
          if (SHIFT > 0){
            int rhk = (wh == 7) ? ((prk >= 4) ? 2 : 1) : 0;
            int rwk = (ww == 7) ? ((pck >= 4) ? 2 : 1) : 0;
            if (idq != rhk * 3 + rwk) v -= 100.f;
          }
          vv[j] = v;
          mx = fmaxf(mx, v);
        }
        for (int mm = 1; mm < 16; mm <<= 1) mx = fmaxf(mx, __shfl_xor(mx, mm, 64));
        float sum = 0.f;
        #pragma unroll
        for (int j = 0; j < 4; j++){ vv[j] = __expf(vv[j] - mx); sum += vv[j]; }
        for (int mm = 1; mm < 16; mm <<= 1) sum += __shfl_xor(sum, mm, 64);
        float inv = 1.0f / sum;
        #pragma unroll
        for (int j = 0; j < 4; j++) p_s[wave][rq][j * 16 + fr] = f2bf(vv[j] * inv);
      }
    }
    __syncthreads();   // p_s + vT_s visible

    // O = P(64x64) * V(64x32)
    f32x4 o[4][2];
    #pragma unroll
    for (int i = 0; i < 4; i++){ o[i][0] = z4; o[i][1] = z4; }
    #pragma unroll
    for (int ks = 0; ks < 2; ks++){
      bf16x8 pa[4], vb[2];
      #pragma unroll
      for (int i = 0; i < 4; i++) pa[i] = *(const bf16x8*)&p_s[wave][i * 16 + fr][ks * 32 + fq * 8];
      #pragma unroll
      for (int j = 0; j < 2; j++) vb[j] = *(const bf16x8*)&vT_s[wave][j * 16 + fr][ks * 32 + fq * 8];
      #pragma unroll
      for (int i = 0; i < 4; i++)
        #pragma unroll
        for (int j = 0; j < 2; j++)
          o[i][j] = __builtin_amdgcn_mfma_f32_16x16x32_bf16(pa[i], vb[j], o[i][j], 0, 0, 0);
    }
    // store: row rq -> token tmap[rq], channel = head*32 + j*16 + fr
    #pragma unroll
    for (int i = 0; i < 4; i++)
      #pragma unroll
      for (int j = 0; j < 2; j++)
        #pragma unroll
        for (int rr = 0; rr < 4; rr++){
          int rq = i * 16 + fq * 4 + rr;
          int t = tmap[rq];
          out[(size_t)t * 256 + head * 32 + j * 16 + fr] = f2bf(o[i][j][rr]);
        }
    __syncthreads();   // before next head overwrites LDS
  }
}

// ---------------- host ----------------
extern "C" void kernel_launch(void* const* d_in, const int* in_sizes, int n_in,
                              void* d_out, int out_size, void* d_ws, size_t ws_size,
                              hipStream_t stream){
  (void)in_sizes; (void)n_in; (void)out_size; (void)ws_size;
  const float* x      = (const float*)d_in[0];
  const float* cv1_w  = (const float*)d_in[1];
  const float* cv1_bn = (const float*)d_in[2];
  const float* cv2_w  = (const float*)d_in[3];
  const float* cv2_bn = (const float*)d_in[4];
  const float* cv3_w  = (const float*)d_in[5];
  const float* cv3_bn = (const float*)d_in[6];
  const float* n1g = (const float*)d_in[7];
  const float* n1b = (const float*)d_in[8];
  const float* qkvw = (const float*)d_in[9];
  const float* qkvb = (const float*)d_in[10];
  const float* pw  = (const float*)d_in[11];
  const float* pb  = (const float*)d_in[12];
  const float* rpb = (const float*)d_in[13];
  const float* n2g = (const float*)d_in[14];
  const float* n2b = (const float*)d_in[15];
  const float* f1w = (const float*)d_in[16];
  const float* f1b = (const float*)d_in[17];
  const float* f2w = (const float*)d_in[18];
  const float* f2b = (const float*)d_in[19];

  char* ws = (char*)d_ws;
  const size_t MB = 1024 * 1024;
  // layout (peak 360 MB):
  // [0,32)   ln_o / xT low / yF
  // [32,64)  at_o / xT high
  // [64,192) qkvB / hB
  // [192,256) yS fp32 residual stream
  // [256,320) x1 fp32
  // [320,328) wp bf16 weights
  // [328,360) y2 (cv2 out bf16)
  u16*   xT   = (u16*)(ws);
  u16*   ln_o = (u16*)(ws);
  u16*   yF   = (u16*)(ws);
  u16*   at_o = (u16*)(ws + 32 * MB);
  u16*   qkvB = (u16*)(ws + 64 * MB);
  u16*   hB   = qkvB;
  float* yS   = (float*)(ws + 192 * MB);
  float* x1   = (float*)(ws + 256 * MB);
  u16*   wp   = (u16*)(ws + 320 * MB);
  u16*   y2   = (u16*)(ws + 328 * MB);

  u16* wCv1 = wp;
  u16* wCv2 = wp + 131072;
  u16* wCv3 = wp + 262144;
  u16* wQkv = wp + 524288;
  u16* wPrj = wp + 917504;
  u16* wF1  = wp + 1048576;
  u16* wF2  = wp + 1572864;

  // one batched weight-convert launch (sizes in float4 units)
  {
    CvtP cp;
    cp.src[0] = cv1_w; cp.dst[0] = wCv1;
    cp.src[1] = cv2_w; cp.dst[1] = wCv2;
    cp.src[2] = cv3_w; cp.dst[2] = wCv3;
    cp.src[3] = qkvw;  cp.dst[3] = wQkv;
    cp.src[4] = pw;    cp.dst[4] = wPrj;
    cp.src[5] = f1w;   cp.dst[5] = wF1;
    cp.src[6] = f2w;   cp.dst[6] = wF2;
    int sz[7] = {32768, 32768, 65536, 98304, 32768, 131072, 131072};
    cp.cum[0] = 0;
    for (int i = 0; i < 7; i++) cp.cum[i + 1] = cp.cum[i] + sz[i];
    k_cvt7<<<(cp.cum[7] + 255) / 256, 256, 0, stream>>>(cp);
  }

  k_xpose<<<dim3(64, 8, 16), 256, 0, stream>>>(x, xT);

  const int M = 65536;
  auto gemm = [&](int mode, const u16* A, const u16* A2, const u16* W, int K, int N,
                  const float* bias, int bnN, const float* resid, int ldR,
                  float* outF, int ldF, u16* outB, int ldB, int colB){
    int NB = N / 128;
    GemmP p{A, A2, W, K, N, NB, bias, bnN, resid, ldR, outF, ldF, outB, ldB, colB};
    int nwg = (M / 128) * NB;
    switch (mode){
      case 0: k_gemm<0><<<nwg, 256, 0, stream>>>(p); break;
      case 1: k_gemm<1><<<nwg, 256, 0, stream>>>(p); break;
      case 2: k_gemm<2><<<nwg, 256, 0, stream>>>(p); break;
      case 3: k_gemm<3><<<nwg, 256, 0, stream>>>(p); break;
      case 4: k_gemm<4><<<nwg, 256, 0, stream>>>(p); break;
      case 5: k_gemm<5><<<nwg, 256, 0, stream>>>(p); break;
      case 6: k_gemm<6><<<nwg, 256, 0, stream>>>(p); break;
    }
  };

  // cv1 -> yS (fp32 residual stream) ; cv2 -> y2 bf16
  gemm(0, xT, nullptr, wCv1, 512, 256, cv1_bn, 256, nullptr, 0, yS, 256, nullptr, 0, 0);
  gemm(1, xT, nullptr, wCv2, 512, 256, cv2_bn, 256, nullptr, 0, nullptr, 0, y2, 256, 0);

  for (int l = 0; l < 2; l++){
    k_ln<<<16384, 256, 0, stream>>>(yS, n1g + l * 256, n1b + l * 256, ln_o);
    gemm(2, ln_o, nullptr, wQkv + l * 196608, 256, 768, qkvb + l * 768, 0, nullptr, 0,
         nullptr, 0, qkvB, 768, 0);
    if (l == 0) k_attn<0><<<1024, 256, 0, stream>>>(qkvB, rpb, at_o);
    else        k_attn<4><<<1024, 256, 0, stream>>>(qkvB, rpb + 1800, at_o);
    gemm(3, at_o, nullptr, wPrj + l * 65536, 256, 256, pb + l * 256, 0, yS, 256,
         x1, 256, nullptr, 0, 0);
    k_ln<<<16384, 256, 0, stream>>>(x1, n2g + l * 256, n2b + l * 256, ln_o);
    gemm(4, ln_o, nullptr, wF1 + l * 262144, 256, 1024, f1b + l * 1024, 0, nullptr, 0,
         nullptr, 0, hB, 1024, 0);
    if (l == 0)
      gemm(3, hB, nullptr, wF2 + l * 262144, 1024, 256, f2b + l * 256, 0, x1, 256,
           yS, 256, nullptr, 0, 0);
    else
      gemm(5, hB, nullptr, wF2 + l * 262144, 1024, 256, f2b + l * 256, 0, x1, 256,
           yS, 256, yF, 256, 0);
  }

  // cv3: A = [yF | y2] (split at k=256) -> BN+SiLU -> d_out fp32 NCHW
  gemm(6, yF, y2, wCv3, 512, 512, cv3_bn, 512, nullptr, 0,
       (float*)d_out, 0, nullptr, 0, 0);
}